// Round 4
// baseline (165.491 us; speedup 1.0000x reference)
//
#include <hip/hip_runtime.h>
#include <cstddef>

#define B_   8
#define H_   96
#define W_   96
#define HW_  9216
#define PIX_ 73728

typedef __attribute__((ext_vector_type(8))) __bf16 bf16x8;
typedef __attribute__((ext_vector_type(4))) float floatx4;
typedef __attribute__((ext_vector_type(8))) unsigned short ushort8;

// ws layout (byte offsets)
#define XT_OFF   0                          // bf16 NHWC x: PIX*64*2
#define WFM_OFF  (XT_OFF + PIX_*64*2)       // main W frags: 18*4*64*8 bf16
#define WFO_OFF  (WFM_OFF + 18*4*64*8*2)    // offs W frags: 18*2*64*8 bf16

#define MSTR 76                             // meta LDS stride (floats): 16B-aligned, 2-way banks

__device__ __forceinline__ unsigned short f2bf(float f) {
    unsigned u = __float_as_uint(f);
    return (unsigned short)((u + 0x7FFFu + ((u >> 16) & 1u)) >> 16);
}
__device__ __forceinline__ float bf2f(unsigned short v) {
    return __uint_as_float((unsigned)v << 16);
}

// ---------------------------------------------------------------------------
// Fused pre-pass: blocks [0,1152) transpose NCHW f32 -> NHWC bf16;
// blocks [1152,1179) pack MFMA A-fragments.
__global__ __launch_bounds__(256) void k_pre(const float* __restrict__ x,
                                             const float* __restrict__ offw,
                                             const float* __restrict__ mw,
                                             const float* __restrict__ convw,
                                             unsigned short* __restrict__ xt,
                                             unsigned short* __restrict__ wfm,
                                             unsigned short* __restrict__ wfo) {
    __shared__ float tile[64 * 65];
    int blk = blockIdx.x;
    int t = threadIdx.x;
    if (blk < 1152) {
        int bb  = blk / 144;
        int sp0 = (blk % 144) * 64;
        int s = t & 63, cg = t >> 6;
        #pragma unroll
        for (int i = 0; i < 16; ++i) {
            int c = cg * 16 + i;
            tile[c * 65 + s] = x[(size_t)(bb * 64 + c) * HW_ + sp0 + s];
        }
        __syncthreads();
        int cl4 = (t & 15) * 4, sg = t >> 4;
        #pragma unroll
        for (int i = 0; i < 4; ++i) {
            int s2 = sg * 4 + i;
            uint2 wd;
            wd.x = (unsigned)f2bf(tile[cl4 * 65 + s2])       | ((unsigned)f2bf(tile[(cl4 + 1) * 65 + s2]) << 16);
            wd.y = (unsigned)f2bf(tile[(cl4 + 2) * 65 + s2]) | ((unsigned)f2bf(tile[(cl4 + 3) * 65 + s2]) << 16);
            *(uint2*)(xt + (size_t)(bb * HW_ + sp0 + s2) * 64 + cl4) = wd;
        }
        return;
    }
    int g = (blk - 1152) * 256 + t;
    if (g < 4608) {
        int lane = g & 63, mtks = g >> 6;
        int mt = mtks & 3, ks = mtks >> 2;
        int o = mt * 16 + (lane & 15), quad = lane >> 4;
        unsigned v[8];
        #pragma unroll
        for (int j = 0; j < 8; ++j) {
            int k = ks * 32 + quad * 8 + j;
            int tt = k / 64, c = k % 64;
            v[j] = f2bf(convw[(size_t)(o * 64 + c) * 9 + tt]);
        }
        uint4 pk;
        pk.x = v[0] | (v[1] << 16); pk.y = v[2] | (v[3] << 16);
        pk.z = v[4] | (v[5] << 16); pk.w = v[6] | (v[7] << 16);
        *(uint4*)(wfm + (size_t)g * 8) = pk;
    } else if (g < 4608 + 2304) {
        int g2 = g - 4608;
        int lane = g2 & 63, mtks = g2 >> 6;
        int mt = mtks & 1, ks = mtks >> 1;
        int m = mt * 16 + (lane & 15), quad = lane >> 4;
        unsigned v[8];
        #pragma unroll
        for (int j = 0; j < 8; ++j) {
            int k = ks * 32 + quad * 8 + j;
            int tt = k / 64, c = k % 64;
            float f = 0.f;
            if (m < 18)      f = offw[(size_t)(m * 64 + c) * 9 + tt];
            else if (m < 27) f = mw[(size_t)((m - 18) * 64 + c) * 9 + tt];
            v[j] = f2bf(f);
        }
        uint4 pk;
        pk.x = v[0] | (v[1] << 16); pk.y = v[2] | (v[3] << 16);
        pk.z = v[4] | (v[5] << 16); pk.w = v[6] | (v[7] << 16);
        *(uint4*)(wfo + (size_t)g2 * 8) = pk;
    }
}

// ---------------------------------------------------------------------------
// Fused: offset/mod conv (MFMA) -> bilinear meta -> main contraction (MFMA).
// One wave owns 32 pixels. Register double-buffered gather pipeline; XCD swizzle.
__global__ __launch_bounds__(128) void k_fused(const unsigned short* __restrict__ xt,
                                               const unsigned short* __restrict__ wfo,
                                               const unsigned short* __restrict__ wfm,
                                               const float* __restrict__ offb,
                                               const float* __restrict__ mb,
                                               const float* __restrict__ convb,
                                               float* __restrict__ out) {
    __shared__ float s_off[2][32 * 33];      // [wave][m][pix]
    __shared__ float s_meta[2][32 * MSTR];   // [wave][pix][n*8 words]
    int tid = threadIdx.x, blk = blockIdx.x;
    int w = tid >> 6, lane = tid & 63, col = lane & 15, quad = lane >> 4;
    int q8 = quad * 8;
    // XCD swizzle: b = blk & 7 so each XCD's L2 caches one batch image.
    int b  = blk & 7;
    int sb = (blk >> 3) * 64 + w * 32;
    const unsigned short* xtb = xt + (size_t)b * HW_ * 64;

    int sj[2], hj[2], wj[2];
    #pragma unroll
    for (int jj = 0; jj < 2; ++jj) {
        sj[jj] = sb + jj * 16 + col;
        hj[jj] = sj[jj] / 96; wj[jj] = sj[jj] % 96;
    }

    // ---- phase 1: offset/mod conv GEMM (M=32, K=576), tap double-buffer ----
    floatx4 aoff[2][2];
    #pragma unroll
    for (int jj = 0; jj < 2; ++jj)
        #pragma unroll
        for (int mt = 0; mt < 2; ++mt) aoff[jj][mt] = (floatx4){0.f, 0.f, 0.f, 0.f};

    uint4 V[2][2][2];   // [buf][jj][ksl]
    auto ldtap = [&](int tt, int buf) {
        int dh = tt / 3 - 1, dw = tt % 3 - 1;
        #pragma unroll
        for (int jj = 0; jj < 2; ++jj) {
            int h2 = hj[jj] + dh, w2 = wj[jj] + dw;
            bool ok = ((unsigned)h2 < 96u) && ((unsigned)w2 < 96u);
            const unsigned short* pb = xtb + ((size_t)(h2 * 96 + w2) * 64 + q8);
            V[buf][jj][0] = ok ? *(const uint4*)(pb)      : make_uint4(0, 0, 0, 0);
            V[buf][jj][1] = ok ? *(const uint4*)(pb + 32) : make_uint4(0, 0, 0, 0);
        }
    };
    ldtap(0, 0);
    #pragma unroll 1
    for (int t = 0; t < 9; ++t) {
        int cur = t & 1, alt = cur ^ 1;
        ldtap((t < 8) ? t + 1 : 8, alt);
        #pragma unroll
        for (int ksl = 0; ksl < 2; ++ksl) {
            int ks = t * 2 + ksl;
            bf16x8 a0 = *(const bf16x8*)(wfo + ((size_t)(ks * 2 + 0) * 64 + lane) * 8);
            bf16x8 a1 = *(const bf16x8*)(wfo + ((size_t)(ks * 2 + 1) * 64 + lane) * 8);
            #pragma unroll
            for (int jj = 0; jj < 2; ++jj) {
                union { uint4 u; bf16x8 b; } uu; uu.u = V[cur][jj][ksl];
                aoff[jj][0] = __builtin_amdgcn_mfma_f32_16x16x32_bf16(a0, uu.b, aoff[jj][0], 0, 0, 0);
                aoff[jj][1] = __builtin_amdgcn_mfma_f32_16x16x32_bf16(a1, uu.b, aoff[jj][1], 0, 0, 0);
            }
        }
    }
    #pragma unroll
    for (int jj = 0; jj < 2; ++jj)
        #pragma unroll
        for (int mt = 0; mt < 2; ++mt)
            #pragma unroll
            for (int r = 0; r < 4; ++r)
                s_off[w][(mt * 16 + quad * 4 + r) * 33 + jj * 16 + col] = aoff[jj][mt][r];
    __syncthreads();

    // ---- phase 2: bilinear metadata ----
    int gl = lane >> 5;
    int pp = lane & 31;
    int sP = sb + pp, hh = sP / 96, ww = sP % 96;
    #pragma unroll
    for (int i = 0; i < 5; ++i) {
        int n = gl + 2 * i;
        if (n <= 8) {
            float ox = s_off[w][n * 33 + pp]        + offb[n];
            float oy = s_off[w][(9 + n) * 33 + pp]  + offb[9 + n];
            float mv = s_off[w][(18 + n) * 33 + pp] + mb[n];
            float mod = 1.f / (1.f + __expf(-mv));
            float px = ox + (float)(hh + 1) + (float)(n / 3 - 1);
            float py = oy + (float)(ww + 1) + (float)(n % 3 - 1);
            float flx = floorf(px), fly = floorf(py);
            float tlxf = fminf(fmaxf(flx,       0.f), 97.f);
            float tlyf = fminf(fmaxf(fly,       0.f), 97.f);
            float brxf = fminf(fmaxf(flx + 1.f, 0.f), 97.f);
            float bryf = fminf(fmaxf(fly + 1.f, 0.f), 97.f);
            float pcx  = fminf(fmaxf(px, 0.f), 97.f);
            float pcy  = fminf(fmaxf(py, 0.f), 97.f);
            float gx0 = 1.f + tlxf - pcx;
            float gx1 = 1.f - (brxf - pcx);
            float gy0 = 1.f + tlyf - pcy;
            float gy1 = 1.f - (bryf - pcy);
            int tlx = (int)tlxf, tly = (int)tlyf, brx = (int)brxf, bry = (int)bryf;
            int   qxs[4] = {tlx, tlx, brx, brx};
            int   qys[4] = {tly, bry, tly, bry};
            float gs[4]  = {gx0 * gy0, gx0 * gy1, gx1 * gy0, gx1 * gy1};
            int   idx[4]; float gg[4];
            #pragma unroll
            for (int c4 = 0; c4 < 4; ++c4) {
                bool okc = (qxs[c4] >= 1) && (qxs[c4] <= 96) && (qys[c4] >= 1) && (qys[c4] <= 96);
                idx[c4] = okc ? ((qxs[c4] - 1) * W_ + (qys[c4] - 1)) : 0;
                gg[c4]  = okc ? gs[c4] * mod : 0.f;
            }
            int4 iv;   iv.x = idx[0]; iv.y = idx[1]; iv.z = idx[2]; iv.w = idx[3];
            float4 gv; gv.x = gg[0];  gv.y = gg[1];  gv.z = gg[2];  gv.w = gg[3];
            *(int4*)  &s_meta[w][pp * MSTR + n * 8]     = iv;
            *(float4*)&s_meta[w][pp * MSTR + n * 8 + 4] = gv;
        }
    }
    __syncthreads();

    // ---- phase 3: main GEMM (M=64, K=576), pipelined direct-frag gather ----
    floatx4 acc[2][4];
    #pragma unroll
    for (int jj = 0; jj < 2; ++jj)
        #pragma unroll
        for (int mt = 0; mt < 4; ++mt) acc[jj][mt] = (floatx4){0.f, 0.f, 0.f, 0.f};

    int4 idxA[2]; float4 gA[2];
    #pragma unroll
    for (int jj = 0; jj < 2; ++jj) {
        int mo = (jj * 16 + col) * MSTR;
        idxA[jj] = *(const int4*)  &s_meta[w][mo];
        gA[jj]   = *(const float4*)&s_meta[w][mo + 4];
    }
    uint4 C[2][4];
    C[0][0] = *(const uint4*)(xtb + (size_t)idxA[0].x * 64 + q8);
    C[0][1] = *(const uint4*)(xtb + (size_t)idxA[0].y * 64 + q8);
    C[0][2] = *(const uint4*)(xtb + (size_t)idxA[0].z * 64 + q8);
    C[0][3] = *(const uint4*)(xtb + (size_t)idxA[0].w * 64 + q8);

    #pragma unroll 1
    for (int n = 0; n < 9; ++n) {
        int np = (n < 8) ? n + 1 : 8;
        int4 idxN[2]; float4 gN[2];
        #pragma unroll
        for (int jj = 0; jj < 2; ++jj) {
            int mo = (jj * 16 + col) * MSTR + np * 8;
            idxN[jj] = *(const int4*)  &s_meta[w][mo];
            gN[jj]   = *(const float4*)&s_meta[w][mo + 4];
        }
        #pragma unroll
        for (int ksl = 0; ksl < 2; ++ksl) {
            int ks = n * 2 + ksl;
            bf16x8 af[4];
            #pragma unroll
            for (int mt = 0; mt < 4; ++mt)
                af[mt] = *(const bf16x8*)(wfm + ((size_t)(ks * 4 + mt) * 64 + lane) * 8);
            #pragma unroll
            for (int jj = 0; jj < 2; ++jj) {
                const int st  = ksl * 2 + jj;
                const int cur = st & 1, alt = cur ^ 1;
                // prefetch next step's corners: (0,0)->(0,1)->(1,0)->(1,1)->next-n(0,0)
                {
                    const int pnk = (jj == 0) ? ksl : (ksl ^ 1);
                    int4 ix = (st == 3) ? idxN[0] : idxA[jj ^ 1];
                    const int cboN = pnk * 32 + q8;
                    C[alt][0] = *(const uint4*)(xtb + (size_t)ix.x * 64 + cboN);
                    C[alt][1] = *(const uint4*)(xtb + (size_t)ix.y * 64 + cboN);
                    C[alt][2] = *(const uint4*)(xtb + (size_t)ix.z * 64 + cboN);
                    C[alt][3] = *(const uint4*)(xtb + (size_t)ix.w * 64 + cboN);
                }
                union { uint4 u; ushort8 s; } c0, c1, c2, c3;
                c0.u = C[cur][0]; c1.u = C[cur][1]; c2.u = C[cur][2]; c3.u = C[cur][3];
                float gx = gA[jj].x, gy = gA[jj].y, gz = gA[jj].z, gw = gA[jj].w;
                ushort8 ov;
                #pragma unroll
                for (int j = 0; j < 8; ++j) {
                    float v = gx * bf2f(c0.s[j]);
                    v = fmaf(gy, bf2f(c1.s[j]), v);
                    v = fmaf(gz, bf2f(c2.s[j]), v);
                    v = fmaf(gw, bf2f(c3.s[j]), v);
                    ov[j] = f2bf(v);
                }
                union { ushort8 u; bf16x8 b; } ub; ub.u = ov;
                #pragma unroll
                for (int mt = 0; mt < 4; ++mt)
                    acc[jj][mt] = __builtin_amdgcn_mfma_f32_16x16x32_bf16(af[mt], ub.b, acc[jj][mt], 0, 0, 0);
            }
        }
        idxA[0] = idxN[0]; idxA[1] = idxN[1];
        gA[0] = gN[0]; gA[1] = gN[1];
    }

    // ---- epilogue ----
    #pragma unroll
    for (int mt = 0; mt < 4; ++mt) {
        float4 cb4 = *(const float4*)&convb[mt * 16 + quad * 4];
        #pragma unroll
        for (int jj = 0; jj < 2; ++jj) {
            #pragma unroll
            for (int r = 0; r < 4; ++r) {
                int o = mt * 16 + quad * 4 + r;
                float bias = (r == 0) ? cb4.x : (r == 1) ? cb4.y : (r == 2) ? cb4.z : cb4.w;
                out[(size_t)(b * 64 + o) * HW_ + sj[jj]] = acc[jj][mt][r] + bias;
            }
        }
    }
}

// ---------------------------------------------------------------------------
extern "C" void kernel_launch(void* const* d_in, const int* in_sizes, int n_in,
                              void* d_out, int out_size, void* d_ws, size_t ws_size,
                              hipStream_t stream) {
    const float* x     = (const float*)d_in[0];
    const float* offw  = (const float*)d_in[1];
    const float* offb  = (const float*)d_in[2];
    const float* mw    = (const float*)d_in[3];
    const float* mb    = (const float*)d_in[4];
    const float* convw = (const float*)d_in[5];
    const float* convb = (const float*)d_in[6];
    char* ws = (char*)d_ws;
    unsigned short* xt16 = (unsigned short*)(ws + XT_OFF);
    unsigned short* wfm  = (unsigned short*)(ws + WFM_OFF);
    unsigned short* wfo  = (unsigned short*)(ws + WFO_OFF);
    float* out = (float*)d_out;

    k_pre  <<<dim3(1179), dim3(256), 0, stream>>>(x, offw, mw, convw, xt16, wfm, wfo);
    k_fused<<<dim3(1152), dim3(128), 0, stream>>>(xt16, wfo, wfm, offb, mb, convb, out);
}